// Round 5
// baseline (1222.320 us; speedup 1.0000x reference)
//
#include <hip/hip_runtime.h>
#include <stdint.h>

#define NROWS 500000
#define NROWS4 125000
#define NCLS 100
#define NBINS 15
#define NBKT 2048           // L1 buckets: key = bits>>19 (11-bit)
#define NSUB 64             // sub-bucket = bits[18:13], quantum 8192 ULP
#define B1 8
#define CH1 15625           // 125000/8 float4s per hist1 block
#define B2 20
#define CH2 6250            // 125000/20 float4s per scan2 block
#define HSZ (NBINS * NSUB)  // 960
#define H1REC (3 * NBKT)    // 6144 words per (blk,class) hist1 record
#define S2REC (3 * HSZ)     // 2880 words per (blk,class) scan2 record

__device__ __forceinline__ int rank_target(int b) {
    if (b == 0) return 0;
    const float step = 500000.0f / 15.0f;   // float32-rounded, mimics jnp.linspace
    return (int)floorf((float)b * step);
}

// Pass 1: row softmax of logits [N][C], write transposed probsT [C][N]
__global__ __launch_bounds__(256) void k_softmax_t(const float* __restrict__ logits,
                                                   float* __restrict__ probsT) {
    __shared__ float tile[64][101];
    __shared__ float red[256];
    __shared__ float mx[64];
    __shared__ float inv[64];
    const int row0 = blockIdx.x * 64;
    const int rows = min(64, NROWS - row0);
    const int t = threadIdx.x;
    const int total = rows * NCLS;
    for (int k = t; k < total; k += 256) {
        int r = k / NCLS, c = k - r * NCLS;
        tile[r][c] = logits[(size_t)(row0 + r) * NCLS + c];
    }
    __syncthreads();
    const int r = t >> 2, q = t & 3;   // 4 threads per row
    if (r < rows) {
        float m = -1e30f;
        #pragma unroll
        for (int c = 0; c < 25; ++c) m = fmaxf(m, tile[r][q * 25 + c]);
        red[t] = m;
    }
    __syncthreads();
    if (r < rows && q == 0)
        mx[r] = fmaxf(fmaxf(red[t], red[t + 1]), fmaxf(red[t + 2], red[t + 3]));
    __syncthreads();
    if (r < rows) {
        float m = mx[r], s = 0.f;
        #pragma unroll
        for (int c = 0; c < 25; ++c) {
            float e = __expf(tile[r][q * 25 + c] - m);
            tile[r][q * 25 + c] = e;
            s += e;
        }
        red[t] = s;
    }
    __syncthreads();
    if (r < rows && q == 0)
        inv[r] = 1.0f / (red[t] + red[t + 1] + red[t + 2] + red[t + 3]);
    __syncthreads();
    const int shift = (rows == 64) ? 4 : 3;
    const int gq = 1 << shift;
    const int ng = NCLS << shift;
    for (int k = t; k < ng; k += 256) {
        int c = k >> shift, g = k & (gq - 1);
        int rr = g << 2;
        float4 o;
        o.x = tile[rr + 0][c] * inv[rr + 0];
        o.y = tile[rr + 1][c] * inv[rr + 1];
        o.z = tile[rr + 2][c] * inv[rr + 2];
        o.w = tile[rr + 3][c] * inv[rr + 3];
        *(float4*)(probsT + (size_t)c * NROWS + row0 + rr) = o;
    }
}

// Pass 2: per-class L1 bucket {n, sumT, sumQ} histogram (11-bit key),
// non-atomic flush to private copy per blockIdx.x
__global__ __launch_bounds__(256) void k_hist1(const float4* __restrict__ probsT4,
                                               int* __restrict__ hist1p) {
    __shared__ int   hn[NBKT];
    __shared__ float hT[NBKT];
    __shared__ float hQ[NBKT];
    const int c = blockIdx.y, t = threadIdx.x;
    for (int i = t; i < NBKT; i += 256) { hn[i] = 0; hT[i] = 0.f; hQ[i] = 0.f; }
    __syncthreads();
    const size_t base = (size_t)c * NROWS4;
    const int start = blockIdx.x * CH1;
    const int end = min(NROWS4, start + CH1);
    for (int i = start + t; i < end; i += 256) {
        float4 v = probsT4[base + i];
        float val[4] = {v.x, v.y, v.z, v.w};
        #pragma unroll
        for (int e = 0; e < 4; ++e) {
            int key = (int)(__float_as_uint(val[e]) >> 19);
            atomicAdd(&hn[key], 1);
            atomicAdd(&hT[key], val[e]);
            atomicAdd(&hQ[key], val[e] * val[e]);
        }
    }
    __syncthreads();
    int* on = hist1p + (size_t)(blockIdx.x * NCLS + c) * H1REC;
    float* oT = (float*)(on + NBKT);
    float* oQ = (float*)(on + 2 * NBKT);
    for (int i = t; i < NBKT; i += 256) { on[i] = hn[i]; oT[i] = hT[i]; oQ[i] = hQ[i]; }
}

// Select L1 bucket per rank target; block prefix-scan (shfl, double for T/Q)
// gives exact {N,T,Q} below each target bucket edge + class totals. Also
// zeroes accLab (saves the memset dispatch).
__global__ __launch_bounds__(256) void k_sel1(const int* __restrict__ hist1p,
                                              int* __restrict__ tgt,
                                              int* __restrict__ below,
                                              int* __restrict__ owner,
                                              double* __restrict__ edgeT,
                                              double* __restrict__ edgeQ,
                                              double* __restrict__ accC,
                                              float* __restrict__ accLab) {
    __shared__ int    wsn[4];
    __shared__ double wst[4], wsq[4];
    __shared__ int stgt[NBINS], sbelow[NBINS];
    __shared__ double sET[NBINS], sEQ[NBINS];
    const int c = blockIdx.x, t = threadIdx.x;
    int   ln[8] = {0,0,0,0,0,0,0,0};
    float lT[8] = {0,0,0,0,0,0,0,0};
    float lQ[8] = {0,0,0,0,0,0,0,0};
    for (int k = 0; k < B1; ++k) {
        const int* bn = hist1p + (size_t)(k * NCLS + c) * H1REC;
        const float* bT = (const float*)(bn + NBKT);
        const float* bQ = (const float*)(bn + 2 * NBKT);
        #pragma unroll
        for (int j = 0; j < 2; ++j) {
            int4   n4 = ((const int4*)bn)[t * 2 + j];
            float4 T4 = ((const float4*)bT)[t * 2 + j];
            float4 Q4 = ((const float4*)bQ)[t * 2 + j];
            ln[j*4+0] += n4.x; ln[j*4+1] += n4.y; ln[j*4+2] += n4.z; ln[j*4+3] += n4.w;
            lT[j*4+0] += T4.x; lT[j*4+1] += T4.y; lT[j*4+2] += T4.z; lT[j*4+3] += T4.w;
            lQ[j*4+0] += Q4.x; lQ[j*4+1] += Q4.y; lQ[j*4+2] += Q4.z; lQ[j*4+3] += Q4.w;
        }
    }
    int sn = 0; double sT = 0.0, sQ = 0.0;
    #pragma unroll
    for (int i = 0; i < 8; ++i) { sn += ln[i]; sT += (double)lT[i]; sQ += (double)lQ[i]; }
    // block-wide exclusive prefix of per-thread totals
    const int lane = t & 63, w = t >> 6;
    int in_ = sn; double iT = sT, iQ = sQ;
    #pragma unroll
    for (int d = 1; d < 64; d <<= 1) {
        int    an = __shfl_up(in_, d, 64);
        double aT = __shfl_up(iT, d, 64);
        double aQ = __shfl_up(iQ, d, 64);
        if (lane >= d) { in_ += an; iT += aT; iQ += aQ; }
    }
    if (lane == 63) { wsn[w] = in_; wst[w] = iT; wsq[w] = iQ; }
    __syncthreads();
    int offn = 0; double offT = 0.0, offQ = 0.0;
    #pragma unroll
    for (int j = 0; j < 4; ++j)
        if (j < w) { offn += wsn[j]; offT += wst[j]; offQ += wsq[j]; }
    const int    cum0n = offn + in_ - sn;
    const double cum0T = offT + iT - sT;
    const double cum0Q = offQ + iQ - sQ;
    for (int b = 0; b < NBINS; ++b) {
        const int f = rank_target(b);
        int cc = cum0n; double dT = cum0T, dQ = cum0Q;
        #pragma unroll
        for (int i = 0; i < 8; ++i) {
            if (f >= cc && f < cc + ln[i]) {
                stgt[b] = t * 8 + i; sbelow[b] = cc; sET[b] = dT; sEQ[b] = dQ;
            }
            cc += ln[i]; dT += (double)lT[i]; dQ += (double)lQ[i];
        }
    }
    __syncthreads();
    if (t == 255) {   // grand totals (inclusive scan of last thread)
        accC[c * 2 + 0] = offT + iT;
        accC[c * 2 + 1] = offQ + iQ;
    }
    if (t == 0) {
        int ow = 0;
        for (int b = 0; b < NBINS; ++b) {
            if (b == 0 || stgt[b] != stgt[b - 1]) ow = b;
            owner[c * NBINS + b] = ow;
            tgt[c * NBINS + b] = stgt[b];
            below[c * NBINS + b] = sbelow[b];
            edgeT[c * NBINS + b] = sET[b];
            edgeQ[c * NBINS + b] = sEQ[b];
        }
    }
    if (t < NBINS * 2) accLab[c * NBINS * 2 + t] = 0.f;
}

// Pass 3 (lite): sub-histogram {n,T,Q} of target-bucket members only.
// No min-trick — edge baselines come from sel1's bucket prefix.
__global__ __launch_bounds__(256) void k_scan2(const float4* __restrict__ probsT4,
                                               const int* __restrict__ tgt,
                                               int* __restrict__ scan2p) {
    __shared__ int stg[16];
    __shared__ int hn[HSZ];
    __shared__ float hT[HSZ];
    __shared__ float hQ[HSZ];
    const int c = blockIdx.y, t = threadIdx.x;
    if (t < 16) stg[t] = (t < NBINS) ? tgt[c * NBINS + t] : 0x7FFFFFFF;
    for (int i = t; i < HSZ; i += 256) { hn[i] = 0; hT[i] = 0.f; hQ[i] = 0.f; }
    __syncthreads();
    const size_t base = (size_t)c * NROWS4;
    const int start = blockIdx.x * CH2;
    const int end = min(NROWS4, start + CH2);
    for (int i = start + t; i < end; i += 256) {
        float4 v = probsT4[base + i];
        float val[4] = {v.x, v.y, v.z, v.w};
        #pragma unroll
        for (int e = 0; e < 4; ++e) {
            unsigned bits = __float_as_uint(val[e]);
            int k1 = (int)(bits >> 19);
            int idx = 0;                      // lower_bound over sorted stg
            idx += (stg[idx + 7] < k1) ? 8 : 0;
            idx += (stg[idx + 3] < k1) ? 4 : 0;
            idx += (stg[idx + 1] < k1) ? 2 : 0;
            idx += (stg[idx] < k1) ? 1 : 0;
            if (idx < NBINS && stg[idx] == k1) {
                int s = idx * NSUB + (int)((bits >> 13) & (NSUB - 1));
                atomicAdd(&hn[s], 1);
                atomicAdd(&hT[s], val[e]);
                atomicAdd(&hQ[s], val[e] * val[e]);
            }
        }
    }
    __syncthreads();
    int* on = scan2p + (size_t)(blockIdx.x * NCLS + c) * S2REC;
    float* oT = (float*)(on + HSZ);
    float* oQ = (float*)(on + 2 * HSZ);
    for (int i = t; i < HSZ; i += 256) { on[i] = hn[i]; oT[i] = hT[i]; oQ[i] = hQ[i]; }
}

// Select sub-bucket (1 wave per boundary, shfl prefix); assemble exact
// cumulative {N, T, Q} at the boundary
__global__ __launch_bounds__(64) void k_sel2(const int* __restrict__ scan2p,
                                             const int* __restrict__ tgt,
                                             const int* __restrict__ below,
                                             const int* __restrict__ owner,
                                             const double* __restrict__ edgeT,
                                             const double* __restrict__ edgeQ,
                                             float* __restrict__ bounds,
                                             int* __restrict__ cumN,
                                             double* __restrict__ cumT,
                                             double* __restrict__ cumQ) {
    const int b = blockIdx.x, c = blockIdx.y, t = threadIdx.x;   // t < 64
    const int ow = owner[c * NBINS + b];
    int nj = 0; float Tj = 0.f, Qj = 0.f;
    for (int k = 0; k < B2; ++k) {
        const int* p = scan2p + (size_t)(k * NCLS + c) * S2REC + ow * NSUB + t;
        nj += p[0];
        Tj += ((const float*)p)[HSZ];
        Qj += ((const float*)p)[2 * HSZ];
    }
    const int own = nj;
    #pragma unroll
    for (int d = 1; d < 64; d <<= 1) {
        int   an = __shfl_up(nj, d, 64);
        float aT = __shfl_up(Tj, d, 64);
        float aQ = __shfl_up(Qj, d, 64);
        if (t >= d) { nj += an; Tj += aT; Qj += aQ; }
    }
    const int bel = below[c * NBINS + b];
    const int lr = rank_target(b) - bel;
    if (lr >= nj - own && lr < nj) {
        unsigned bits = ((unsigned)tgt[c * NBINS + b] << 19) | ((unsigned)t << 13) | 0x1FFFu;
        bounds[c * NBINS + b] = __uint_as_float(bits);
        cumN[c * NBINS + b] = bel + nj;
        cumT[c * NBINS + b] = edgeT[c * NBINS + b] + (double)Tj;
        cumQ[c * NBINS + b] = edgeQ[c * NBINS + b] + (double)Qj;
    }
}

// Pass 4: label correction — only elements with lab=1 (their label's class)
__global__ __launch_bounds__(256) void k_label(const float* __restrict__ probsT,
                                               const int* __restrict__ labels,
                                               const float* __restrict__ bounds,
                                               float* __restrict__ accLab) {
    const int n = blockIdx.x * 256 + threadIdx.x;
    if (n >= NROWS) return;
    const int c = labels[n];
    const float conf = probsT[(size_t)c * NROWS + n];
    const float* bd = bounds + c * NBINS;
    if (conf > bd[0]) {
        int idx = 0;
        #pragma unroll
        for (int b = 1; b < NBINS; ++b) idx += (conf > bd[b]) ? 1 : 0;
        atomicAdd(&accLab[(c * NBINS + idx) * 2 + 0], 1.0f);
        atomicAdd(&accLab[(c * NBINS + idx) * 2 + 1], conf);
    }
}

// Pass 5: closed-form LOO combine in double
__global__ __launch_bounds__(256) void k_final(const double* __restrict__ accC,
                                               const int* __restrict__ cumN,
                                               const double* __restrict__ cumT,
                                               const double* __restrict__ cumQ,
                                               const float* __restrict__ accLab,
                                               float* __restrict__ out) {
    __shared__ double red[256];
    const int t = threadIdx.x;
    double local = 0.0;
    for (int k = t; k < NCLS * NBINS; k += 256) {
        int c = k / NBINS, b = k - c * NBINS;
        double n, T, Q;
        if (b < NBINS - 1) {
            n = (double)(cumN[k + 1] - cumN[k]);
            T = cumT[k + 1] - cumT[k];
            Q = cumQ[k + 1] - cumQ[k];
        } else {
            n = (double)(NROWS - cumN[k]);
            T = accC[c * 2 + 0] - cumT[k];
            Q = accC[c * 2 + 1] - cumQ[k];
        }
        double S = accLab[k * 2 + 0], T1 = accLab[k * 2 + 1];
        if (n > 1.5) {
            double inv = 1.0 / (n - 1.0);
            double a0 = S * inv, a1 = (S - 1.0) * inv;
            local += Q - 2.0 * a0 * T + 2.0 * T1 * inv + (n - S) * a0 * a0 + S * a1 * a1;
        }
    }
    red[t] = local;
    __syncthreads();
    for (int s = 128; s; s >>= 1) {
        if (t < s) red[t] += red[t + s];
        __syncthreads();
    }
    if (t == 0) out[0] = (float)(red[0] / ((double)NROWS * (double)NCLS));
}

extern "C" void kernel_launch(void* const* d_in, const int* in_sizes, int n_in,
                              void* d_out, int out_size, void* d_ws, size_t ws_size,
                              hipStream_t stream) {
    const float* logits = (const float*)d_in[0];
    const int* labels = (const int*)d_in[1];
    float* out = (float*)d_out;
    char* ws = (char*)d_ws;
    size_t off = 0;
    auto alloc = [&](size_t bytes) -> void* {
        off = (off + 255) & ~(size_t)255;
        void* p = ws + off;
        off += bytes;
        return p;
    };
    float* probsT = (float*)alloc((size_t)NCLS * NROWS * 4);               // 200 MB
    // aliased region: hist1p (hist1->sel1) reused as scan2p (scan2->sel2)
    size_t h1bytes = (size_t)B1 * NCLS * H1REC * 4;                        // 19.7 MB
    size_t s2bytes = (size_t)B2 * NCLS * S2REC * 4;                        // 23.0 MB
    int* hist1p = (int*)alloc(h1bytes > s2bytes ? h1bytes : s2bytes);
    int* scan2p = hist1p;
    int*    tgt     = (int*)alloc((size_t)NCLS * NBINS * 4);
    int*    below   = (int*)alloc((size_t)NCLS * NBINS * 4);
    int*    owner   = (int*)alloc((size_t)NCLS * NBINS * 4);
    double* edgeT   = (double*)alloc((size_t)NCLS * NBINS * 8);
    double* edgeQ   = (double*)alloc((size_t)NCLS * NBINS * 8);
    double* accC    = (double*)alloc((size_t)NCLS * 2 * 8);
    float*  bounds  = (float*)alloc((size_t)NCLS * NBINS * 4);
    int*    cumN    = (int*)alloc((size_t)NCLS * NBINS * 4);
    double* cumT    = (double*)alloc((size_t)NCLS * NBINS * 8);
    double* cumQ    = (double*)alloc((size_t)NCLS * NBINS * 8);
    float*  accLab  = (float*)alloc((size_t)NCLS * NBINS * 2 * 4);
    if (off > ws_size) {
        hipMemsetAsync(d_out, 0xFF, 4, stream);   // NaN sentinel
        return;
    }

    k_softmax_t<<<(NROWS + 63) / 64, 256, 0, stream>>>(logits, probsT);
    k_hist1<<<dim3(B1, NCLS), 256, 0, stream>>>((const float4*)probsT, hist1p);
    k_sel1<<<NCLS, 256, 0, stream>>>(hist1p, tgt, below, owner, edgeT, edgeQ,
                                     accC, accLab);
    k_scan2<<<dim3(B2, NCLS), 256, 0, stream>>>((const float4*)probsT, tgt, scan2p);
    k_sel2<<<dim3(NBINS, NCLS), 64, 0, stream>>>(scan2p, tgt, below, owner,
                                                 edgeT, edgeQ, bounds, cumN, cumT, cumQ);
    k_label<<<(NROWS + 255) / 256, 256, 0, stream>>>(probsT, labels, bounds, accLab);
    k_final<<<1, 256, 0, stream>>>(accC, cumN, cumT, cumQ, accLab, out);
}